// Round 7
// baseline (508.547 us; speedup 1.0000x reference)
//
#include <hip/hip_runtime.h>
#include <math.h>

// ---------------------------------------------------------------------------
// MultiScaleAdaptiveElasticityLossWithLame
// deformation_field: (2, 3, 160, 192, 160) f32
// image:             (2, 1, 160, 192, 160) f32
// out: scalar f32 = sum over 3 scales of mean(weight * elastic_energy)
//
// R7 scale-0: barrier-free register streamer, v3.
//  - y+-1 via wave shuffle of center regs (lane +-8); only wave-edge rows
//    (ly&7 in {0,7}) load ym/yp from global (L1-resident).
//  - centers prefetched TWO planes ahead (pc/cc/nc/nn rotation, unroll 4
//    renames the rotation) so compute never waits on HBM.
//  - z+-1 via lane shuffle (R4/R6-proven), edge z-lanes load scalars.
// ---------------------------------------------------------------------------

#define LAMBDA_0 1.0f
#define MU_0 1.0f
#define KAPPA_LAMBDA 0.5f
#define KAPPA_MU 0.5f
#define BASE_WEIGHT 1.0f
#define GRADIENT_SCALING 0.1f

typedef float v4f __attribute__((ext_vector_type(4)));

constexpr int S_TY = 32;   // y rows per block tile
constexpr int S_TZ = 32;   // z per block tile (8 groups of 4)
constexpr int S_CX = 8;    // x planes per block

__global__ __launch_bounds__(256, 3)
void elasticity_stream_shfl_kernel(const float* __restrict__ def,
                                   const float* __restrict__ img,
                                   int X, int Y, int Z,
                                   int nby, int nbz, int nbx,
                                   float inv_n, float* __restrict__ out) {
    int t = blockIdx.x;
    const int bx = t % nbx; t /= nbx;
    const int bz = t % nbz; t /= nbz;
    const int by = t % nby; t /= nby;
    const int b = t;

    const int tid = threadIdx.x;
    const int zg = tid & 7;      // 8 z-groups of 4 -> 32 z
    const int ly = tid >> 3;     // 32 y rows
    const int lane = tid & 63;
    const int lyw = lane >> 3;   // y row within wave, 0..7
    const int laneM = (lane - 1) & 63;      // z-1 neighbor (zg>0)
    const int laneP = (lane + 1) & 63;      // z+1 neighbor (zg<7)
    const int laneYm = (lyw > 0) ? (lane - 8) : lane;   // y-1 neighbor
    const int laneYp = (lyw < 7) ? (lane + 8) : lane;   // y+1 neighbor

    const long long vol = (long long)X * Y * Z;
    const long long sX = (long long)Y * Z;
    const float* __restrict__ p0 = def + ((long long)b * 3 + 0) * vol;
    const float* __restrict__ p1 = def + ((long long)b * 3 + 1) * vol;
    const float* __restrict__ p2 = def + ((long long)b * 3 + 2) * vol;
    const float* __restrict__ p3 = img + (long long)b * vol;

    const int gy = by * S_TY + ly;
    const int gz0 = bz * S_TZ + 4 * zg;
    const int x0 = bx * S_CX;

    const long long offC  = (long long)gy * Z + gz0;
    const long long offYm = (long long)max(gy - 1, 0) * Z + gz0;
    const long long offYp = (long long)min(gy + 1, Y - 1) * Z + gz0;
    const long long offZm = offC - ((gz0 > 0) ? 1 : 0);
    const long long offZp = offC + ((gz0 + 4 < Z) ? 4 : 3);

    const bool ylo = (gy == 0), yhi = (gy == Y - 1);
    const bool zlo = (gz0 == 0), zhi = (gz0 + 4 == Z);
    const bool zem = (zg == 0),  zep = (zg == 7);
    const bool yEdgeM = (lyw == 0) && !ylo;   // needs global ym load
    const bool yEdgeP = (lyw == 7) && !yhi;   // needs global yp load

    // persistent plane-center state: 4 sets x 4 fields x v4f = 64 VGPR
    v4f pc[4], cc[4], nc[4], nn[4];
    {
        const long long o_ = (long long)max(x0 - 1, 0) * sX;
        pc[0] = *(const v4f*)(p0 + o_ + offC);
        pc[1] = *(const v4f*)(p1 + o_ + offC);
        pc[2] = *(const v4f*)(p2 + o_ + offC);
        pc[3] = *(const v4f*)(p3 + o_ + offC);
    }
    {
        const long long o_ = (long long)x0 * sX;
        cc[0] = *(const v4f*)(p0 + o_ + offC);
        cc[1] = *(const v4f*)(p1 + o_ + offC);
        cc[2] = *(const v4f*)(p2 + o_ + offC);
        cc[3] = *(const v4f*)(p3 + o_ + offC);
    }
    {
        const long long o_ = (long long)min(x0 + 1, X - 1) * sX;
        nc[0] = *(const v4f*)(p0 + o_ + offC);
        nc[1] = *(const v4f*)(p1 + o_ + offC);
        nc[2] = *(const v4f*)(p2 + o_ + offC);
        nc[3] = *(const v4f*)(p3 + o_ + offC);
    }

    float acc = 0.f;
#pragma unroll 4
    for (int i = 0; i < S_CX; ++i) {
        const int x = x0 + i;
        const bool xlo = (x == 0), xhi = (x == X - 1);
        const long long oC = (long long)x * sX;
        const long long oNN = (long long)min(x + 2, X - 1) * sX;

        // ---- issue memory early ----
        // wave-edge y rows: load neighbor row (L1/L2-resident)
        v4f ymL[4], ypL[4];
        if (yEdgeM) {
            ymL[0] = *(const v4f*)(p0 + oC + offYm);
            ymL[1] = *(const v4f*)(p1 + oC + offYm);
            ymL[2] = *(const v4f*)(p2 + oC + offYm);
            ymL[3] = *(const v4f*)(p3 + oC + offYm);
        }
        if (yEdgeP) {
            ypL[0] = *(const v4f*)(p0 + oC + offYp);
            ypL[1] = *(const v4f*)(p1 + oC + offYp);
            ypL[2] = *(const v4f*)(p2 + oC + offYp);
            ypL[3] = *(const v4f*)(p3 + oC + offYp);
        }
        // z-halo scalars (edge z-lanes only)
        float zmS[4], zpS[4];
        if (zem) {
            zmS[0] = p0[oC + offZm]; zmS[1] = p1[oC + offZm];
            zmS[2] = p2[oC + offZm]; zmS[3] = p3[oC + offZm];
        }
        if (zep) {
            zpS[0] = p0[oC + offZp]; zpS[1] = p1[oC + offZp];
            zpS[2] = p2[oC + offZp]; zpS[3] = p3[oC + offZp];
        }
        // prefetch centers two planes ahead (consumed next-next iteration)
        nn[0] = *(const v4f*)(p0 + oNN + offC);
        nn[1] = *(const v4f*)(p1 + oNN + offC);
        nn[2] = *(const v4f*)(p2 + oNN + offC);
        nn[3] = *(const v4f*)(p3 + oNN + offC);

        // ---- gradients (pc/cc/nc all register-resident) ----
        v4f gxA[4], gyA[4], gzA[4];
#pragma unroll
        for (int f = 0; f < 4; ++f) {
            v4f c = cc[f];
            gxA[f] = xlo ? (nc[f] - c)
                         : (xhi ? (c - pc[f]) : 0.5f * (nc[f] - pc[f]));

            // y+-1 from wave shuffle of neighbor row's center regs
            v4f ymv, ypv;
#pragma unroll
            for (int j = 0; j < 4; ++j) {
                ymv[j] = __shfl(c[j], laneYm, 64);
                ypv[j] = __shfl(c[j], laneYp, 64);
            }
            if (yEdgeM) ymv = ymL[f];
            if (yEdgeP) ypv = ypL[f];
            gyA[f] = ylo ? (ypv - c)
                         : (yhi ? (c - ymv) : 0.5f * (ypv - ymv));

            // z+-1 from z-neighbor lane
            float zmv = __shfl(c[3], laneM, 64);
            float zpv = __shfl(c[0], laneP, 64);
            float zm = zem ? zmS[f] : zmv;
            float zp = zep ? zpS[f] : zpv;
            v4f gz;
            gz[0] = zlo ? (c[1] - c[0]) : 0.5f * (c[1] - zm);
            gz[1] = 0.5f * (c[2] - c[0]);
            gz[2] = 0.5f * (c[3] - c[1]);
            gz[3] = zhi ? (c[3] - c[2]) : 0.5f * (zp - c[2]);
            gzA[f] = gz;
        }

        // ---- energy ----
#pragma unroll
        for (int j = 0; j < 4; ++j) {
            float Exx = gxA[0][j], Eyy = gyA[1][j], Ezz = gzA[2][j];
            float Exy = 0.5f * (gyA[0][j] + gxA[1][j]);
            float Exz = 0.5f * (gzA[0][j] + gxA[2][j]);
            float Eyz = 0.5f * (gzA[1][j] + gyA[2][j]);
            float tr = Exx + Eyy + Ezz;
            float g = sqrtf(gxA[3][j] * gxA[3][j] + gyA[3][j] * gyA[3][j] +
                            gzA[3][j] * gzA[3][j]);
            float lam = LAMBDA_0 + KAPPA_LAMBDA * g;
            float mu  = MU_0 + KAPPA_MU * g;
            float energy = 0.5f * lam * tr * tr +
                           mu * (Exx * Exx + Eyy * Eyy + Ezz * Ezz +
                                 2.0f * (Exy * Exy + Exz * Exz + Eyz * Eyz));
            acc += (BASE_WEIGHT + GRADIENT_SCALING * g) * energy;
        }

        // rotate center sets (renamed away by unroll 4)
#pragma unroll
        for (int f = 0; f < 4; ++f) { pc[f] = cc[f]; cc[f] = nc[f]; nc[f] = nn[f]; }
    }

    float val = acc * inv_n;
    for (int off = 32; off > 0; off >>= 1)
        val += __shfl_down(val, off, 64);
    __shared__ float smem[4];
    const int wid = (int)(threadIdx.x >> 6);
    if ((threadIdx.x & 63) == 0) smem[wid] = val;
    __syncthreads();
    if (threadIdx.x == 0)
        atomicAdd(out, smem[0] + smem[1] + smem[2] + smem[3]);
}

// --------- fused downsample: all 8 maps (B*3 def + B img), R3 indexing ------
__global__ void downsample_all8_kernel(const float* __restrict__ def,
                                       const float* __restrict__ img,
                                       float* __restrict__ odef,
                                       float* __restrict__ oimg,
                                       int inX, int inY, int inZ,
                                       int outX, int outY, int outZ,
                                       float rx, float ry, float rz) {
    long long pervol = (long long)outX * outY * outZ;
    long long total = 8LL * pervol;
    long long idx = (long long)blockIdx.x * blockDim.x + threadIdx.x;
    if (idx >= total) return;

    int m = (int)(idx / pervol);
    long long r = idx % pervol;
    int z = (int)(r % outZ);
    long long t = r / outZ;
    int y = (int)(t % outY);
    int x = (int)(t / outY);

    long long invol = (long long)inX * inY * inZ;
    const float* src;
    float* dst;
    if (m < 6) { src = def + (long long)m * invol;       dst = odef + (long long)m * pervol; }
    else       { src = img + (long long)(m - 6) * invol; dst = oimg + (long long)(m - 6) * pervol; }

    float cx = (float)x * rx;
    float cy = (float)y * ry;
    float cz = (float)z * rz;
    int ix0 = (int)floorf(cx), iy0 = (int)floorf(cy), iz0 = (int)floorf(cz);
    float wx = cx - (float)ix0, wy = cy - (float)iy0, wz = cz - (float)iz0;
    int ix1 = min(ix0 + 1, inX - 1);
    int iy1 = min(iy0 + 1, inY - 1);
    int iz1 = min(iz0 + 1, inZ - 1);

    long long sYZ = (long long)inY * inZ;
    long long bx0 = (long long)ix0 * sYZ, bx1 = (long long)ix1 * sYZ;
    long long by0 = (long long)iy0 * inZ, by1 = (long long)iy1 * inZ;

    float v000 = src[bx0 + by0 + iz0], v001 = src[bx0 + by0 + iz1];
    float v010 = src[bx0 + by1 + iz0], v011 = src[bx0 + by1 + iz1];
    float v100 = src[bx1 + by0 + iz0], v101 = src[bx1 + by0 + iz1];
    float v110 = src[bx1 + by1 + iz0], v111 = src[bx1 + by1 + iz1];

    float a00 = v000 * (1.f - wx) + v100 * wx;
    float a01 = v001 * (1.f - wx) + v101 * wx;
    float a10 = v010 * (1.f - wx) + v110 * wx;
    float a11 = v011 * (1.f - wx) + v111 * wx;
    float b0 = a00 * (1.f - wy) + a10 * wy;
    float b1 = a01 * (1.f - wy) + a11 * wy;
    dst[r] = b0 * (1.f - wz) + b1 * wz;
}

// ----------------- gather loss kernel (scales 1,2) --------------------------
__global__ void elasticity_loss_v4_kernel(const float* __restrict__ def,
                                          const float* __restrict__ img,
                                          int B, int X, int Y, int Z,
                                          float inv_n,
                                          float* __restrict__ out) {
    const int Zg = Z >> 2;
    long long total = (long long)B * X * Y * Zg;
    long long idx = (long long)blockIdx.x * blockDim.x + threadIdx.x;
    float val = 0.f;
    if (idx < total) {
        int zg = (int)(idx % Zg);
        long long t = idx / Zg;
        int y = (int)(t % Y);
        t /= Y;
        int x = (int)(t % X);
        int b = (int)(t / X);
        int z0 = zg << 2;

        long long vol = (long long)X * Y * Z;
        const float* base0 = def + ((long long)b * 3 + 0) * vol;
        const float* base1 = def + ((long long)b * 3 + 1) * vol;
        const float* base2 = def + ((long long)b * 3 + 2) * vol;
        const float* base3 = img + (long long)b * vol;
        const float* bases[4] = {base0, base1, base2, base3};

        long long sX = (long long)Y * Z;
        long long c = (long long)x * sX + (long long)y * Z + z0;
        long long cxm = (x > 0) ? c - sX : c;
        long long cxp = (x < X - 1) ? c + sX : c;
        long long cym = (y > 0) ? c - Z : c;
        long long cyp = (y < Y - 1) ? c + Z : c;
        long long czm = (z0 > 0) ? c - 1 : c;
        long long czp = (z0 + 4 < Z) ? c + 4 : c;

        float C[4][4], XM[4][4], XP[4][4], YM[4][4], YP[4][4];
        float ZM[4], ZP[4];
#pragma unroll
        for (int f = 0; f < 4; ++f) {
            const float* p = bases[f];
            float4 tc = *(const float4*)(p + c);
            float4 txm = *(const float4*)(p + cxm);
            float4 txp = *(const float4*)(p + cxp);
            float4 tym = *(const float4*)(p + cym);
            float4 typ = *(const float4*)(p + cyp);
            ZM[f] = p[czm];
            ZP[f] = p[czp];
            C[f][0] = tc.x;  C[f][1] = tc.y;  C[f][2] = tc.z;  C[f][3] = tc.w;
            XM[f][0] = txm.x; XM[f][1] = txm.y; XM[f][2] = txm.z; XM[f][3] = txm.w;
            XP[f][0] = txp.x; XP[f][1] = txp.y; XP[f][2] = txp.z; XP[f][3] = txp.w;
            YM[f][0] = tym.x; YM[f][1] = tym.y; YM[f][2] = tym.z; YM[f][3] = tym.w;
            YP[f][0] = typ.x; YP[f][1] = typ.y; YP[f][2] = typ.z; YP[f][3] = typ.w;
        }

        const bool xlo = (x == 0), xhi = (x == X - 1);
        const bool ylo = (y == 0), yhi = (y == Y - 1);
        const bool zlo = (z0 == 0), zhi = (z0 + 4 == Z);

        float GX[4][4], GY[4][4], GZ[4][4];
#pragma unroll
        for (int f = 0; f < 4; ++f) {
#pragma unroll
            for (int i = 0; i < 4; ++i) {
                GX[f][i] = xlo ? (XP[f][i] - C[f][i])
                               : (xhi ? (C[f][i] - XM[f][i])
                                      : 0.5f * (XP[f][i] - XM[f][i]));
                GY[f][i] = ylo ? (YP[f][i] - C[f][i])
                               : (yhi ? (C[f][i] - YM[f][i])
                                      : 0.5f * (YP[f][i] - YM[f][i]));
            }
            GZ[f][0] = zlo ? (C[f][1] - C[f][0]) : 0.5f * (C[f][1] - ZM[f]);
            GZ[f][1] = 0.5f * (C[f][2] - C[f][0]);
            GZ[f][2] = 0.5f * (C[f][3] - C[f][1]);
            GZ[f][3] = zhi ? (C[f][3] - C[f][2]) : 0.5f * (ZP[f] - C[f][2]);
        }

        float acc = 0.f;
#pragma unroll
        for (int i = 0; i < 4; ++i) {
            float Exx = GX[0][i], Eyy = GY[1][i], Ezz = GZ[2][i];
            float Exy = 0.5f * (GY[0][i] + GX[1][i]);
            float Exz = 0.5f * (GZ[0][i] + GX[2][i]);
            float Eyz = 0.5f * (GZ[1][i] + GY[2][i]);
            float tr = Exx + Eyy + Ezz;
            float g = sqrtf(GX[3][i] * GX[3][i] + GY[3][i] * GY[3][i] +
                            GZ[3][i] * GZ[3][i]);
            float lam = LAMBDA_0 + KAPPA_LAMBDA * g;
            float mu  = MU_0 + KAPPA_MU * g;
            float energy = 0.5f * lam * tr * tr +
                           mu * (Exx * Exx + Eyy * Eyy + Ezz * Ezz +
                                 2.0f * (Exy * Exy + Exz * Exz + Eyz * Eyz));
            float wgt = BASE_WEIGHT + GRADIENT_SCALING * g;
            acc += wgt * energy;
        }
        val = acc * inv_n;
    }

    for (int off = 32; off > 0; off >>= 1)
        val += __shfl_down(val, off, 64);
    __shared__ float smem[8];
    int lane = threadIdx.x & 63;
    int wid = (int)(threadIdx.x >> 6);
    if (lane == 0) smem[wid] = val;
    __syncthreads();
    if (threadIdx.x == 0) {
        float s = 0.f;
        int nw = (int)(blockDim.x >> 6);
        for (int i = 0; i < nw; ++i) s += smem[i];
        atomicAdd(out, s);
    }
}

static void launch_loss_v4(const float* def, const float* img, int B, int X,
                           int Y, int Z, float* out, hipStream_t stream) {
    const int BLOCK = 256;
    long long nvox = (long long)B * X * Y * Z;
    long long total = nvox >> 2;
    float inv_n = (float)(1.0 / (double)nvox);
    int grid = (int)((total + BLOCK - 1) / BLOCK);
    elasticity_loss_v4_kernel<<<grid, BLOCK, 0, stream>>>(def, img, B, X, Y, Z,
                                                          inv_n, out);
}

extern "C" void kernel_launch(void* const* d_in, const int* in_sizes, int n_in,
                              void* d_out, int out_size, void* d_ws, size_t ws_size,
                              hipStream_t stream) {
    const float* def = (const float*)d_in[0];   // (2,3,160,192,160)
    const float* img = (const float*)d_in[1];   // (2,1,160,192,160)
    float* out = (float*)d_out;

    const int B = 2;
    const int X0 = 160, Y0 = 192, Z0 = 160;

    hipMemsetAsync(out, 0, sizeof(float), stream);

    const int BLOCK = 256;

    // ---------------- scale 0: shuffle streamer ----------------
    {
        long long nvox = (long long)B * X0 * Y0 * Z0;
        float inv_n = (float)(1.0 / (double)nvox);
        int nby = Y0 / S_TY;   // 6
        int nbz = Z0 / S_TZ;   // 5
        int nbx = X0 / S_CX;   // 20
        int grid = B * nby * nbz * nbx;   // 1200
        elasticity_stream_shfl_kernel<<<grid, 256, 0, stream>>>(def, img,
                                                                X0, Y0, Z0,
                                                                nby, nbz, nbx,
                                                                inv_n, out);
    }

    // workspace layout
    const int X2 = 80, Y2 = 96, Z2 = 80;
    const int X4 = 40, Y4 = 48, Z4 = 40;
    long long vol2 = (long long)X2 * Y2 * Z2;
    long long vol4 = (long long)X4 * Y4 * Z4;

    float* def2 = (float*)d_ws;
    float* img2 = def2 + (long long)B * 3 * vol2;
    float* def4 = img2 + (long long)B * vol2;
    float* img4 = def4 + (long long)B * 3 * vol4;

    // ---------------- scale 1 (x2 downsample) ----------------
    {
        float rx = (float)((double)(X0 - 1) / (double)(X2 - 1));
        float ry = (float)((double)(Y0 - 1) / (double)(Y2 - 1));
        float rz = (float)((double)(Z0 - 1) / (double)(Z2 - 1));
        long long total = 8LL * vol2;
        int g = (int)((total + BLOCK - 1) / BLOCK);
        downsample_all8_kernel<<<g, BLOCK, 0, stream>>>(def, img, def2, img2,
                                                        X0, Y0, Z0, X2, Y2, Z2,
                                                        rx, ry, rz);
        launch_loss_v4(def2, img2, B, X2, Y2, Z2, out, stream);
    }

    // ---------------- scale 2 (x4 downsample, from original) ----------------
    {
        float rx = (float)((double)(X0 - 1) / (double)(X4 - 1));
        float ry = (float)((double)(Y0 - 1) / (double)(Y4 - 1));
        float rz = (float)((double)(Z0 - 1) / (double)(Z4 - 1));
        long long total = 8LL * vol4;
        int g = (int)((total + BLOCK - 1) / BLOCK);
        downsample_all8_kernel<<<g, BLOCK, 0, stream>>>(def, img, def4, img4,
                                                        X0, Y0, Z0, X4, Y4, Z4,
                                                        rx, ry, rz);
        launch_loss_v4(def4, img4, B, X4, Y4, Z4, out, stream);
    }
}

// Round 8
// 305.729 us; speedup vs baseline: 1.6634x; 1.6634x over previous
//
#include <hip/hip_runtime.h>
#include <math.h>

// ---------------------------------------------------------------------------
// MultiScaleAdaptiveElasticityLossWithLame
// deformation_field: (2, 3, 160, 192, 160) f32
// image:             (2, 1, 160, 192, 160) f32
// out: scalar f32 = sum over 3 scales of mean(weight * elastic_energy)
//
// R8 scale-0: barrier-free register streamer v4 ("reg3").
//  - R6 structure (unconditional y-row loads, z via lane shuffle), but ALL
//    loads prefetched >=1 plane ahead of use: ym/yp one plane ahead into
//    persistent regs, centers two planes ahead, z-halo scalars one ahead.
//  - fully unrolled 8-plane loop -> all rotations renamed statically.
//  - NO conditionally-initialized arrays of vectors (R7's 573 MB scratch
//    regression); z-halo conditionals are scalars only (R6-proven).
// Tail: R3's downsample + gather-loss structure verbatim (best known).
// ---------------------------------------------------------------------------

#define LAMBDA_0 1.0f
#define MU_0 1.0f
#define KAPPA_LAMBDA 0.5f
#define KAPPA_MU 0.5f
#define BASE_WEIGHT 1.0f
#define GRADIENT_SCALING 0.1f

typedef float v4f __attribute__((ext_vector_type(4)));

constexpr int S_TY = 32;   // y rows per block tile
constexpr int S_TZ = 32;   // z per block tile (8 groups of 4)
constexpr int S_CX = 8;    // x planes per block

__global__ __launch_bounds__(256, 2)
void elasticity_stream_reg3_kernel(const float* __restrict__ def,
                                   const float* __restrict__ img,
                                   int X, int Y, int Z,
                                   int nby, int nbz, int nbx,
                                   float inv_n, float* __restrict__ out) {
    int t = blockIdx.x;
    const int bx = t % nbx; t /= nbx;
    const int bz = t % nbz; t /= nbz;
    const int by = t % nby; t /= nby;
    const int b = t;

    const int tid = threadIdx.x;
    const int zg = tid & 7;     // 8 z-groups of 4 -> 32 z
    const int ly = tid >> 3;    // 32 y rows
    const int lane = tid & 63;
    const int laneM = (lane - 1) & 63;
    const int laneP = (lane + 1) & 63;

    const long long vol = (long long)X * Y * Z;
    const long long sX = (long long)Y * Z;
    const float* __restrict__ p0 = def + ((long long)b * 3 + 0) * vol;
    const float* __restrict__ p1 = def + ((long long)b * 3 + 1) * vol;
    const float* __restrict__ p2 = def + ((long long)b * 3 + 2) * vol;
    const float* __restrict__ p3 = img + (long long)b * vol;

    const int gy = by * S_TY + ly;
    const int gz0 = bz * S_TZ + 4 * zg;
    const int x0 = bx * S_CX;

    const long long offC  = (long long)gy * Z + gz0;
    const long long offYm = (long long)max(gy - 1, 0) * Z + gz0;
    const long long offYp = (long long)min(gy + 1, Y - 1) * Z + gz0;
    const long long offZm = offC - ((gz0 > 0) ? 1 : 0);
    const long long offZp = offC + ((gz0 + 4 < Z) ? 4 : 3);

    const bool ylo = (gy == 0), yhi = (gy == Y - 1);
    const bool zlo = (gz0 == 0), zhi = (gz0 + 4 == Z);
    const bool zem = (zg == 0),  zep = (zg == 7);

    // persistent pipelined state (all unconditional):
    //   pc/cc/nc: centers at x-1, x, x+1   (48 VGPR)
    //   ym/yp:    y-neighbor rows at x     (32 VGPR)
    //   zmS/zpS:  z-halo scalars at x      (8 VGPR; conditional SCALARS only)
    v4f pc[4], cc[4], nc[4], ym[4], yp[4];
    float zmS[4] = {0.f, 0.f, 0.f, 0.f};
    float zpS[4] = {0.f, 0.f, 0.f, 0.f};

    // ---- prologue: fill pipeline for plane x0 ----
    {
        const long long oP = (long long)max(x0 - 1, 0) * sX;
        pc[0] = *(const v4f*)(p0 + oP + offC);
        pc[1] = *(const v4f*)(p1 + oP + offC);
        pc[2] = *(const v4f*)(p2 + oP + offC);
        pc[3] = *(const v4f*)(p3 + oP + offC);
        const long long oC = (long long)x0 * sX;
        cc[0] = *(const v4f*)(p0 + oC + offC);
        cc[1] = *(const v4f*)(p1 + oC + offC);
        cc[2] = *(const v4f*)(p2 + oC + offC);
        cc[3] = *(const v4f*)(p3 + oC + offC);
        ym[0] = *(const v4f*)(p0 + oC + offYm);
        ym[1] = *(const v4f*)(p1 + oC + offYm);
        ym[2] = *(const v4f*)(p2 + oC + offYm);
        ym[3] = *(const v4f*)(p3 + oC + offYm);
        yp[0] = *(const v4f*)(p0 + oC + offYp);
        yp[1] = *(const v4f*)(p1 + oC + offYp);
        yp[2] = *(const v4f*)(p2 + oC + offYp);
        yp[3] = *(const v4f*)(p3 + oC + offYp);
        if (zem) {
            zmS[0] = p0[oC + offZm]; zmS[1] = p1[oC + offZm];
            zmS[2] = p2[oC + offZm]; zmS[3] = p3[oC + offZm];
        }
        if (zep) {
            zpS[0] = p0[oC + offZp]; zpS[1] = p1[oC + offZp];
            zpS[2] = p2[oC + offZp]; zpS[3] = p3[oC + offZp];
        }
        const long long oN = (long long)min(x0 + 1, X - 1) * sX;
        nc[0] = *(const v4f*)(p0 + oN + offC);
        nc[1] = *(const v4f*)(p1 + oN + offC);
        nc[2] = *(const v4f*)(p2 + oN + offC);
        nc[3] = *(const v4f*)(p3 + oN + offC);
    }

    float acc = 0.f;
#pragma unroll
    for (int i = 0; i < S_CX; ++i) {
        const int x = x0 + i;
        const bool xlo = (x == 0), xhi = (x == X - 1);
        const long long oN1 = (long long)min(x + 1, X - 1) * sX;  // plane x+1
        const long long oN2 = (long long)min(x + 2, X - 1) * sX;  // plane x+2

        // ---- issue ALL next-plane loads first (consumed next iteration) ----
        v4f tnc[4], tym[4], typ[4];
        float tzm[4] = {0.f, 0.f, 0.f, 0.f};
        float tzp[4] = {0.f, 0.f, 0.f, 0.f};
        tnc[0] = *(const v4f*)(p0 + oN2 + offC);
        tnc[1] = *(const v4f*)(p1 + oN2 + offC);
        tnc[2] = *(const v4f*)(p2 + oN2 + offC);
        tnc[3] = *(const v4f*)(p3 + oN2 + offC);
        tym[0] = *(const v4f*)(p0 + oN1 + offYm);
        tym[1] = *(const v4f*)(p1 + oN1 + offYm);
        tym[2] = *(const v4f*)(p2 + oN1 + offYm);
        tym[3] = *(const v4f*)(p3 + oN1 + offYm);
        typ[0] = *(const v4f*)(p0 + oN1 + offYp);
        typ[1] = *(const v4f*)(p1 + oN1 + offYp);
        typ[2] = *(const v4f*)(p2 + oN1 + offYp);
        typ[3] = *(const v4f*)(p3 + oN1 + offYp);
        if (zem) {
            tzm[0] = p0[oN1 + offZm]; tzm[1] = p1[oN1 + offZm];
            tzm[2] = p2[oN1 + offZm]; tzm[3] = p3[oN1 + offZm];
        }
        if (zep) {
            tzp[0] = p0[oN1 + offZp]; tzp[1] = p1[oN1 + offZp];
            tzp[2] = p2[oN1 + offZp]; tzp[3] = p3[oN1 + offZp];
        }

        // ---- gradients: everything register-resident ----
        v4f gxA[4], gyA[4], gzA[4];
#pragma unroll
        for (int f = 0; f < 4; ++f) {
            v4f c = cc[f];
            gxA[f] = xlo ? (nc[f] - c)
                         : (xhi ? (c - pc[f]) : 0.5f * (nc[f] - pc[f]));
            gyA[f] = ylo ? (yp[f] - c)
                         : (yhi ? (c - ym[f]) : 0.5f * (yp[f] - ym[f]));
            // z+-1 from the z-neighbor lane's center registers
            float zmv = __shfl(c[3], laneM, 64);
            float zpv = __shfl(c[0], laneP, 64);
            float zm = zem ? zmS[f] : zmv;
            float zp = zep ? zpS[f] : zpv;
            v4f gz;
            gz[0] = zlo ? (c[1] - c[0]) : 0.5f * (c[1] - zm);
            gz[1] = 0.5f * (c[2] - c[0]);
            gz[2] = 0.5f * (c[3] - c[1]);
            gz[3] = zhi ? (c[3] - c[2]) : 0.5f * (zp - c[2]);
            gzA[f] = gz;
        }

        // ---- energy ----
#pragma unroll
        for (int j = 0; j < 4; ++j) {
            float Exx = gxA[0][j], Eyy = gyA[1][j], Ezz = gzA[2][j];
            float Exy = 0.5f * (gyA[0][j] + gxA[1][j]);
            float Exz = 0.5f * (gzA[0][j] + gxA[2][j]);
            float Eyz = 0.5f * (gzA[1][j] + gyA[2][j]);
            float tr = Exx + Eyy + Ezz;
            float g = sqrtf(gxA[3][j] * gxA[3][j] + gyA[3][j] * gyA[3][j] +
                            gzA[3][j] * gzA[3][j]);
            float lam = LAMBDA_0 + KAPPA_LAMBDA * g;
            float mu  = MU_0 + KAPPA_MU * g;
            float energy = 0.5f * lam * tr * tr +
                           mu * (Exx * Exx + Eyy * Eyy + Ezz * Ezz +
                                 2.0f * (Exy * Exy + Exz * Exz + Eyz * Eyz));
            acc += (BASE_WEIGHT + GRADIENT_SCALING * g) * energy;
        }

        // ---- rotate pipeline (statically renamed by full unroll) ----
#pragma unroll
        for (int f = 0; f < 4; ++f) {
            pc[f] = cc[f]; cc[f] = nc[f]; nc[f] = tnc[f];
            ym[f] = tym[f]; yp[f] = typ[f];
            zmS[f] = tzm[f]; zpS[f] = tzp[f];
        }
    }

    float val = acc * inv_n;
    for (int off = 32; off > 0; off >>= 1)
        val += __shfl_down(val, off, 64);
    __shared__ float smem[4];
    const int wid = (int)(threadIdx.x >> 6);
    if ((threadIdx.x & 63) == 0) smem[wid] = val;
    __syncthreads();
    if (threadIdx.x == 0)
        atomicAdd(out, smem[0] + smem[1] + smem[2] + smem[3]);
}

// ------------------- gather kernels (scales 1,2 + downsample) ---------------
// R3 structure verbatim (best known for the small scales).

__global__ void downsample3d_kernel(const float* __restrict__ in,
                                    float* __restrict__ out,
                                    int nmaps,
                                    int inX, int inY, int inZ,
                                    int outX, int outY, int outZ,
                                    float rx, float ry, float rz) {
    long long total = (long long)nmaps * outX * outY * outZ;
    long long idx = (long long)blockIdx.x * blockDim.x + threadIdx.x;
    if (idx >= total) return;

    int z = (int)(idx % outZ);
    long long t = idx / outZ;
    int y = (int)(t % outY);
    t /= outY;
    int x = (int)(t % outX);
    int m = (int)(t / outX);

    float cx = (float)x * rx;
    float cy = (float)y * ry;
    float cz = (float)z * rz;
    int ix0 = (int)floorf(cx), iy0 = (int)floorf(cy), iz0 = (int)floorf(cz);
    float wx = cx - (float)ix0, wy = cy - (float)iy0, wz = cz - (float)iz0;
    int ix1 = min(ix0 + 1, inX - 1);
    int iy1 = min(iy0 + 1, inY - 1);
    int iz1 = min(iz0 + 1, inZ - 1);

    long long sYZ = (long long)inY * inZ;
    const float* p = in + (long long)m * inX * sYZ;

    long long bx0 = (long long)ix0 * sYZ, bx1 = (long long)ix1 * sYZ;
    long long by0 = (long long)iy0 * inZ, by1 = (long long)iy1 * inZ;

    float v000 = p[bx0 + by0 + iz0], v001 = p[bx0 + by0 + iz1];
    float v010 = p[bx0 + by1 + iz0], v011 = p[bx0 + by1 + iz1];
    float v100 = p[bx1 + by0 + iz0], v101 = p[bx1 + by0 + iz1];
    float v110 = p[bx1 + by1 + iz0], v111 = p[bx1 + by1 + iz1];

    float a00 = v000 * (1.f - wx) + v100 * wx;
    float a01 = v001 * (1.f - wx) + v101 * wx;
    float a10 = v010 * (1.f - wx) + v110 * wx;
    float a11 = v011 * (1.f - wx) + v111 * wx;
    float b0 = a00 * (1.f - wy) + a10 * wy;
    float b1 = a01 * (1.f - wy) + a11 * wy;
    out[idx] = b0 * (1.f - wz) + b1 * wz;
}

__global__ void elasticity_loss_v4_kernel(const float* __restrict__ def,
                                          const float* __restrict__ img,
                                          int B, int X, int Y, int Z,
                                          float inv_n,
                                          float* __restrict__ out) {
    const int Zg = Z >> 2;
    long long total = (long long)B * X * Y * Zg;
    long long idx = (long long)blockIdx.x * blockDim.x + threadIdx.x;
    float val = 0.f;
    if (idx < total) {
        int zg = (int)(idx % Zg);
        long long t = idx / Zg;
        int y = (int)(t % Y);
        t /= Y;
        int x = (int)(t % X);
        int b = (int)(t / X);
        int z0 = zg << 2;

        long long vol = (long long)X * Y * Z;
        const float* base0 = def + ((long long)b * 3 + 0) * vol;
        const float* base1 = def + ((long long)b * 3 + 1) * vol;
        const float* base2 = def + ((long long)b * 3 + 2) * vol;
        const float* base3 = img + (long long)b * vol;
        const float* bases[4] = {base0, base1, base2, base3};

        long long sX = (long long)Y * Z;
        long long c = (long long)x * sX + (long long)y * Z + z0;
        long long cxm = (x > 0) ? c - sX : c;
        long long cxp = (x < X - 1) ? c + sX : c;
        long long cym = (y > 0) ? c - Z : c;
        long long cyp = (y < Y - 1) ? c + Z : c;
        long long czm = (z0 > 0) ? c - 1 : c;
        long long czp = (z0 + 4 < Z) ? c + 4 : c;

        float C[4][4], XM[4][4], XP[4][4], YM[4][4], YP[4][4];
        float ZM[4], ZP[4];
#pragma unroll
        for (int f = 0; f < 4; ++f) {
            const float* p = bases[f];
            float4 tc = *(const float4*)(p + c);
            float4 txm = *(const float4*)(p + cxm);
            float4 txp = *(const float4*)(p + cxp);
            float4 tym = *(const float4*)(p + cym);
            float4 typ = *(const float4*)(p + cyp);
            ZM[f] = p[czm];
            ZP[f] = p[czp];
            C[f][0] = tc.x;  C[f][1] = tc.y;  C[f][2] = tc.z;  C[f][3] = tc.w;
            XM[f][0] = txm.x; XM[f][1] = txm.y; XM[f][2] = txm.z; XM[f][3] = txm.w;
            XP[f][0] = txp.x; XP[f][1] = txp.y; XP[f][2] = txp.z; XP[f][3] = txp.w;
            YM[f][0] = tym.x; YM[f][1] = tym.y; YM[f][2] = tym.z; YM[f][3] = tym.w;
            YP[f][0] = typ.x; YP[f][1] = typ.y; YP[f][2] = typ.z; YP[f][3] = typ.w;
        }

        const bool xlo = (x == 0), xhi = (x == X - 1);
        const bool ylo = (y == 0), yhi = (y == Y - 1);
        const bool zlo = (z0 == 0), zhi = (z0 + 4 == Z);

        float GX[4][4], GY[4][4], GZ[4][4];
#pragma unroll
        for (int f = 0; f < 4; ++f) {
#pragma unroll
            for (int i = 0; i < 4; ++i) {
                GX[f][i] = xlo ? (XP[f][i] - C[f][i])
                               : (xhi ? (C[f][i] - XM[f][i])
                                      : 0.5f * (XP[f][i] - XM[f][i]));
                GY[f][i] = ylo ? (YP[f][i] - C[f][i])
                               : (yhi ? (C[f][i] - YM[f][i])
                                      : 0.5f * (YP[f][i] - YM[f][i]));
            }
            GZ[f][0] = zlo ? (C[f][1] - C[f][0]) : 0.5f * (C[f][1] - ZM[f]);
            GZ[f][1] = 0.5f * (C[f][2] - C[f][0]);
            GZ[f][2] = 0.5f * (C[f][3] - C[f][1]);
            GZ[f][3] = zhi ? (C[f][3] - C[f][2]) : 0.5f * (ZP[f] - C[f][2]);
        }

        float acc = 0.f;
#pragma unroll
        for (int i = 0; i < 4; ++i) {
            float Exx = GX[0][i], Eyy = GY[1][i], Ezz = GZ[2][i];
            float Exy = 0.5f * (GY[0][i] + GX[1][i]);
            float Exz = 0.5f * (GZ[0][i] + GX[2][i]);
            float Eyz = 0.5f * (GZ[1][i] + GY[2][i]);
            float tr = Exx + Eyy + Ezz;
            float g = sqrtf(GX[3][i] * GX[3][i] + GY[3][i] * GY[3][i] +
                            GZ[3][i] * GZ[3][i]);
            float lam = LAMBDA_0 + KAPPA_LAMBDA * g;
            float mu  = MU_0 + KAPPA_MU * g;
            float energy = 0.5f * lam * tr * tr +
                           mu * (Exx * Exx + Eyy * Eyy + Ezz * Ezz +
                                 2.0f * (Exy * Exy + Exz * Exz + Eyz * Eyz));
            float wgt = BASE_WEIGHT + GRADIENT_SCALING * g;
            acc += wgt * energy;
        }
        val = acc * inv_n;
    }

    for (int off = 32; off > 0; off >>= 1)
        val += __shfl_down(val, off, 64);
    __shared__ float smem[8];
    int lane = threadIdx.x & 63;
    int wid = (int)(threadIdx.x >> 6);
    if (lane == 0) smem[wid] = val;
    __syncthreads();
    if (threadIdx.x == 0) {
        float s = 0.f;
        int nw = (int)(blockDim.x >> 6);
        for (int i = 0; i < nw; ++i) s += smem[i];
        atomicAdd(out, s);
    }
}

static void launch_loss_v4(const float* def, const float* img, int B, int X,
                           int Y, int Z, float* out, hipStream_t stream) {
    const int BLOCK = 256;
    long long nvox = (long long)B * X * Y * Z;
    long long total = nvox >> 2;
    float inv_n = (float)(1.0 / (double)nvox);
    int grid = (int)((total + BLOCK - 1) / BLOCK);
    elasticity_loss_v4_kernel<<<grid, BLOCK, 0, stream>>>(def, img, B, X, Y, Z,
                                                          inv_n, out);
}

extern "C" void kernel_launch(void* const* d_in, const int* in_sizes, int n_in,
                              void* d_out, int out_size, void* d_ws, size_t ws_size,
                              hipStream_t stream) {
    const float* def = (const float*)d_in[0];   // (2,3,160,192,160)
    const float* img = (const float*)d_in[1];   // (2,1,160,192,160)
    float* out = (float*)d_out;

    const int B = 2;
    const int X0 = 160, Y0 = 192, Z0 = 160;

    hipMemsetAsync(out, 0, sizeof(float), stream);

    const int BLOCK = 256;

    // ---------------- scale 0: pipelined register streamer ----------------
    {
        long long nvox = (long long)B * X0 * Y0 * Z0;
        float inv_n = (float)(1.0 / (double)nvox);
        int nby = Y0 / S_TY;   // 6
        int nbz = Z0 / S_TZ;   // 5
        int nbx = X0 / S_CX;   // 20
        int grid = B * nby * nbz * nbx;   // 1200
        elasticity_stream_reg3_kernel<<<grid, 256, 0, stream>>>(def, img,
                                                                X0, Y0, Z0,
                                                                nby, nbz, nbx,
                                                                inv_n, out);
    }

    // workspace layout
    const int X2 = 80, Y2 = 96, Z2 = 80;
    const int X4 = 40, Y4 = 48, Z4 = 40;
    long long vol2 = (long long)X2 * Y2 * Z2;
    long long vol4 = (long long)X4 * Y4 * Z4;

    float* def2 = (float*)d_ws;
    float* img2 = def2 + (long long)B * 3 * vol2;
    float* def4 = img2 + (long long)B * vol2;
    float* img4 = def4 + (long long)B * 3 * vol4;

    // ---------------- scale 1 (x2 downsample) ----------------
    {
        float rx = (float)((double)(X0 - 1) / (double)(X2 - 1));
        float ry = (float)((double)(Y0 - 1) / (double)(Y2 - 1));
        float rz = (float)((double)(Z0 - 1) / (double)(Z2 - 1));
        long long td = (long long)B * 3 * vol2;
        int gd = (int)((td + BLOCK - 1) / BLOCK);
        downsample3d_kernel<<<gd, BLOCK, 0, stream>>>(def, def2, B * 3,
                                                      X0, Y0, Z0, X2, Y2, Z2,
                                                      rx, ry, rz);
        long long ti = (long long)B * vol2;
        int gi = (int)((ti + BLOCK - 1) / BLOCK);
        downsample3d_kernel<<<gi, BLOCK, 0, stream>>>(img, img2, B,
                                                      X0, Y0, Z0, X2, Y2, Z2,
                                                      rx, ry, rz);
        launch_loss_v4(def2, img2, B, X2, Y2, Z2, out, stream);
    }

    // ---------------- scale 2 (x4 downsample, from original) ----------------
    {
        float rx = (float)((double)(X0 - 1) / (double)(X4 - 1));
        float ry = (float)((double)(Y0 - 1) / (double)(Y4 - 1));
        float rz = (float)((double)(Z0 - 1) / (double)(Z4 - 1));
        long long td = (long long)B * 3 * vol4;
        int gd = (int)((td + BLOCK - 1) / BLOCK);
        downsample3d_kernel<<<gd, BLOCK, 0, stream>>>(def, def4, B * 3,
                                                      X0, Y0, Z0, X4, Y4, Z4,
                                                      rx, ry, rz);
        long long ti = (long long)B * vol4;
        int gi = (int)((ti + BLOCK - 1) / BLOCK);
        downsample3d_kernel<<<gi, BLOCK, 0, stream>>>(img, img4, B,
                                                      X0, Y0, Z0, X4, Y4, Z4,
                                                      rx, ry, rz);
        launch_loss_v4(def4, img4, B, X4, Y4, Z4, out, stream);
    }
}

// Round 9
// 111.643 us; speedup vs baseline: 4.5551x; 2.7385x over previous
//
#include <hip/hip_runtime.h>
#include <math.h>

// ---------------------------------------------------------------------------
// MultiScaleAdaptiveElasticityLossWithLame
// deformation_field: (2, 3, 160, 192, 160) f32
// image:             (2, 1, 160, 192, 160) f32
// out: scalar f32 = sum over 3 scales of mean(weight * elastic_energy)
//
// R9 = composition of best-measured parts:
//  - scale-0: R3's streaming-x LDS stencil, verbatim (78 us measured).
//  - tail:    R7's fused downsample_all8 (z-innermost, coalesced) + R3's
//             gather loss kernel (R7 tail measured ~22 us vs R3's 38.7).
// Register-pipelined scale-0 variants (R5/R7/R8) all spilled -> abandoned.
// ---------------------------------------------------------------------------

#define LAMBDA_0 1.0f
#define MU_0 1.0f
#define KAPPA_LAMBDA 0.5f
#define KAPPA_MU 0.5f
#define BASE_WEIGHT 1.0f
#define GRADIENT_SCALING 0.1f

// ------------------- streaming-x LDS stencil (scale 0) ---------------------
constexpr int TY = 32;       // y tile
constexpr int TZ = 32;       // z tile (8 z-groups of 4)
constexpr int CX = 10;       // x planes per block
constexpr int PITCH = TZ + 4;        // 36 floats/row: 0..31 = z, 32 = z-1, 33 = z+32
constexpr int ROWS = TY + 2;         // rows 0..33 = y-1 .. y+32
constexpr int FSZ = ROWS * PITCH;    // 1224 floats per field

struct P4 {
    float4 a, b, c, d;
    float ha, hb, hc, hd;
};

__device__ __forceinline__ P4 loadPlane(const float* __restrict__ p0,
                                        const float* __restrict__ p1,
                                        const float* __restrict__ p2,
                                        const float* __restrict__ p3,
                                        long long po, long long ctrOff,
                                        bool hasHalo, long long haloOff) {
    P4 r;
    long long o = po + ctrOff;
    r.a = *(const float4*)(p0 + o);
    r.b = *(const float4*)(p1 + o);
    r.c = *(const float4*)(p2 + o);
    r.d = *(const float4*)(p3 + o);
    r.ha = r.hb = r.hc = r.hd = 0.f;
    if (hasHalo) {
        long long h = po + haloOff;
        r.ha = p0[h]; r.hb = p1[h]; r.hc = p2[h]; r.hd = p3[h];
    }
    return r;
}

__device__ __forceinline__ void storePlane(float* lds, const P4& pr,
                                           int ldsCtr, bool hasHalo, int hIdx) {
    *(float4*)(lds + 0 * FSZ + ldsCtr) = pr.a;
    *(float4*)(lds + 1 * FSZ + ldsCtr) = pr.b;
    *(float4*)(lds + 2 * FSZ + ldsCtr) = pr.c;
    *(float4*)(lds + 3 * FSZ + ldsCtr) = pr.d;
    if (hasHalo) {
        lds[0 * FSZ + hIdx] = pr.ha;
        lds[1 * FSZ + hIdx] = pr.hb;
        lds[2 * FSZ + hIdx] = pr.hc;
        lds[3 * FSZ + hIdx] = pr.hd;
    }
}

__device__ __forceinline__ void unpackC(const P4& p, float d[4][4]) {
    d[0][0] = p.a.x; d[0][1] = p.a.y; d[0][2] = p.a.z; d[0][3] = p.a.w;
    d[1][0] = p.b.x; d[1][1] = p.b.y; d[1][2] = p.b.z; d[1][3] = p.b.w;
    d[2][0] = p.c.x; d[2][1] = p.c.y; d[2][2] = p.c.z; d[2][3] = p.c.w;
    d[3][0] = p.d.x; d[3][1] = p.d.y; d[3][2] = p.d.z; d[3][3] = p.d.w;
}

__global__ void elasticity_stream_kernel(const float* __restrict__ def,
                                         const float* __restrict__ img,
                                         int X, int Y, int Z,
                                         int nby, int nbz, int nbx,
                                         float inv_n, float* __restrict__ out) {
    __shared__ __align__(16) float lds[4 * FSZ];

    int t = blockIdx.x;
    const int bx = t % nbx; t /= nbx;
    const int bz = t % nbz; t /= nbz;
    const int by = t % nby; t /= nby;
    const int b = t;

    const int tz = bz * TZ, ty = by * TY, x0 = bx * CX;
    const int tid = threadIdx.x;
    const int zg = tid & 7;    // 8 z-groups of 4
    const int ly = tid >> 3;   // 0..31

    const long long vol = (long long)X * Y * Z;
    const long long sX = (long long)Y * Z;
    const float* __restrict__ p0 = def + ((long long)b * 3 + 0) * vol;
    const float* __restrict__ p1 = def + ((long long)b * 3 + 1) * vol;
    const float* __restrict__ p2 = def + ((long long)b * 3 + 2) * vol;
    const float* __restrict__ p3 = img + (long long)b * vol;

    const int gy = ty + ly;
    const int gz0 = tz + 4 * zg;
    const long long ctrOff = (long long)gy * Z + gz0;
    const int ldsCtr = (ly + 1) * PITCH + 4 * zg;

    // halo cell assignment: 132 edge cells of the 34x34 plane tile
    const bool hasHalo = (tid < 2 * (TZ + 2) + 2 * TY);   // 132
    int hIdx = 0;
    long long haloOff = 0;
    if (hasHalo) {
        int hr, hc;
        if (tid < TZ + 2)                { hr = 0;      hc = tid; }
        else if (tid < 2 * (TZ + 2))     { hr = TY + 1; hc = tid - (TZ + 2); }
        else if (tid < 2 * (TZ + 2) + TY){ hr = tid - 2 * (TZ + 2) + 1; hc = TZ; }
        else                             { hr = tid - (2 * (TZ + 2) + TY) + 1; hc = TZ + 1; }
        int zl = (hc < TZ) ? hc : ((hc == TZ) ? -1 : TZ);
        int hy = min(max(ty + hr - 1, 0), Y - 1);
        int hz = min(max(tz + zl, 0), Z - 1);
        haloOff = (long long)hy * Z + hz;
        hIdx = hr * PITCH + hc;
    }

    const bool ylo = (gy == 0), yhi = (gy == Y - 1);
    const bool zloE = (gz0 == 0), zhiE = (gz0 + 4 == Z);
    const int zmCol = (zg == 0) ? TZ : (4 * zg - 1);
    const int zpCol = (zg == 7) ? (TZ + 1) : (4 * zg + 4);
    const int rowM = ly * PITCH + 4 * zg;
    const int rowC = (ly + 1) * PITCH;
    const int rowP = (ly + 2) * PITCH + 4 * zg;

    // ---- prologue ----
    float Cprev[4][4], Ccur[4][4], Cnext[4][4];
    {
        long long o = (long long)max(x0 - 1, 0) * sX + ctrOff;
        float4 a = *(const float4*)(p0 + o);
        float4 bq = *(const float4*)(p1 + o);
        float4 c = *(const float4*)(p2 + o);
        float4 d = *(const float4*)(p3 + o);
        Cprev[0][0]=a.x; Cprev[0][1]=a.y; Cprev[0][2]=a.z; Cprev[0][3]=a.w;
        Cprev[1][0]=bq.x;Cprev[1][1]=bq.y;Cprev[1][2]=bq.z;Cprev[1][3]=bq.w;
        Cprev[2][0]=c.x; Cprev[2][1]=c.y; Cprev[2][2]=c.z; Cprev[2][3]=c.w;
        Cprev[3][0]=d.x; Cprev[3][1]=d.y; Cprev[3][2]=d.z; Cprev[3][3]=d.w;
    }
    P4 cur = loadPlane(p0, p1, p2, p3, (long long)x0 * sX, ctrOff, hasHalo, haloOff);
    storePlane(lds, cur, ldsCtr, hasHalo, hIdx);
    unpackC(cur, Ccur);
    __syncthreads();
    P4 pn = loadPlane(p0, p1, p2, p3, (long long)(x0 + 1) * sX, ctrOff, hasHalo, haloOff);

    float acc = 0.f;
    for (int i = 0; i < CX; ++i) {
        const int x = x0 + i;
        const bool xlo = (x == 0), xhi = (x == X - 1);

        // prefetch plane x+2 (consumed as `pn` next iteration)
        P4 q;
        const bool more = (i + 1 < CX);
        if (more) {
            long long xp = min(x + 2, X - 1);
            q = loadPlane(p0, p1, p2, p3, xp * sX, ctrOff, hasHalo, haloOff);
        }

        unpackC(pn, Cnext);

        // gradients from LDS plane (y,z taps) + register planes (x taps)
        float GX[4][4], GY[4][4], GZ[4][4];
#pragma unroll
        for (int f = 0; f < 4; ++f) {
            const float* L = lds + f * FSZ;
            float4 ym = *(const float4*)(L + rowM);
            float4 yp = *(const float4*)(L + rowP);
            float zm = L[rowC + zmCol];
            float zp = L[rowC + zpCol];
            float ymv[4] = {ym.x, ym.y, ym.z, ym.w};
            float ypv[4] = {yp.x, yp.y, yp.z, yp.w};
#pragma unroll
            for (int i2 = 0; i2 < 4; ++i2) {
                float C = Ccur[f][i2];
                GX[f][i2] = xlo ? (Cnext[f][i2] - C)
                                : (xhi ? (C - Cprev[f][i2])
                                       : 0.5f * (Cnext[f][i2] - Cprev[f][i2]));
                GY[f][i2] = ylo ? (ypv[i2] - C)
                                : (yhi ? (C - ymv[i2])
                                       : 0.5f * (ypv[i2] - ymv[i2]));
            }
            GZ[f][0] = zloE ? (Ccur[f][1] - Ccur[f][0]) : 0.5f * (Ccur[f][1] - zm);
            GZ[f][1] = 0.5f * (Ccur[f][2] - Ccur[f][0]);
            GZ[f][2] = 0.5f * (Ccur[f][3] - Ccur[f][1]);
            GZ[f][3] = zhiE ? (Ccur[f][3] - Ccur[f][2]) : 0.5f * (zp - Ccur[f][2]);
        }

#pragma unroll
        for (int i2 = 0; i2 < 4; ++i2) {
            float Exx = GX[0][i2], Eyy = GY[1][i2], Ezz = GZ[2][i2];
            float Exy = 0.5f * (GY[0][i2] + GX[1][i2]);
            float Exz = 0.5f * (GZ[0][i2] + GX[2][i2]);
            float Eyz = 0.5f * (GZ[1][i2] + GY[2][i2]);
            float tr = Exx + Eyy + Ezz;
            float g = sqrtf(GX[3][i2] * GX[3][i2] + GY[3][i2] * GY[3][i2] +
                            GZ[3][i2] * GZ[3][i2]);
            float lam = LAMBDA_0 + KAPPA_LAMBDA * g;
            float mu  = MU_0 + KAPPA_MU * g;
            float energy = 0.5f * lam * tr * tr +
                           mu * (Exx * Exx + Eyy * Eyy + Ezz * Ezz +
                                 2.0f * (Exy * Exy + Exz * Exz + Eyz * Eyz));
            float wgt = BASE_WEIGHT + GRADIENT_SCALING * g;
            acc += wgt * energy;
        }

        if (more) {
            __syncthreads();   // everyone done reading LDS plane x
            storePlane(lds, pn, ldsCtr, hasHalo, hIdx);
            __syncthreads();   // plane x+1 ready
#pragma unroll
            for (int f = 0; f < 4; ++f)
#pragma unroll
                for (int i2 = 0; i2 < 4; ++i2) {
                    Cprev[f][i2] = Ccur[f][i2];
                    Ccur[f][i2] = Cnext[f][i2];
                }
            pn = q;
        }
    }

    float val = acc * inv_n;
    for (int off = 32; off > 0; off >>= 1)
        val += __shfl_down(val, off, 64);
    __shared__ float smem[4];
    int wid = (int)(threadIdx.x >> 6);
    if ((threadIdx.x & 63) == 0) smem[wid] = val;
    __syncthreads();
    if (threadIdx.x == 0) {
        float s = smem[0] + smem[1] + smem[2] + smem[3];
        atomicAdd(out, s);
    }
}

// --------- fused downsample: all 8 maps (B*3 def + B img), z-innermost ------
// R7-proven: coalescing preserved (thread idx innermost over z), one launch
// per scale instead of two.
__global__ void downsample_all8_kernel(const float* __restrict__ def,
                                       const float* __restrict__ img,
                                       float* __restrict__ odef,
                                       float* __restrict__ oimg,
                                       int inX, int inY, int inZ,
                                       int outX, int outY, int outZ,
                                       float rx, float ry, float rz) {
    long long pervol = (long long)outX * outY * outZ;
    long long total = 8LL * pervol;
    long long idx = (long long)blockIdx.x * blockDim.x + threadIdx.x;
    if (idx >= total) return;

    int m = (int)(idx / pervol);
    long long r = idx % pervol;
    int z = (int)(r % outZ);
    long long t = r / outZ;
    int y = (int)(t % outY);
    int x = (int)(t / outY);

    long long invol = (long long)inX * inY * inZ;
    const float* src;
    float* dst;
    if (m < 6) { src = def + (long long)m * invol;       dst = odef + (long long)m * pervol; }
    else       { src = img + (long long)(m - 6) * invol; dst = oimg + (long long)(m - 6) * pervol; }

    float cx = (float)x * rx;
    float cy = (float)y * ry;
    float cz = (float)z * rz;
    int ix0 = (int)floorf(cx), iy0 = (int)floorf(cy), iz0 = (int)floorf(cz);
    float wx = cx - (float)ix0, wy = cy - (float)iy0, wz = cz - (float)iz0;
    int ix1 = min(ix0 + 1, inX - 1);
    int iy1 = min(iy0 + 1, inY - 1);
    int iz1 = min(iz0 + 1, inZ - 1);

    long long sYZ = (long long)inY * inZ;
    long long bx0 = (long long)ix0 * sYZ, bx1 = (long long)ix1 * sYZ;
    long long by0 = (long long)iy0 * inZ, by1 = (long long)iy1 * inZ;

    float v000 = src[bx0 + by0 + iz0], v001 = src[bx0 + by0 + iz1];
    float v010 = src[bx0 + by1 + iz0], v011 = src[bx0 + by1 + iz1];
    float v100 = src[bx1 + by0 + iz0], v101 = src[bx1 + by0 + iz1];
    float v110 = src[bx1 + by1 + iz0], v111 = src[bx1 + by1 + iz1];

    float a00 = v000 * (1.f - wx) + v100 * wx;
    float a01 = v001 * (1.f - wx) + v101 * wx;
    float a10 = v010 * (1.f - wx) + v110 * wx;
    float a11 = v011 * (1.f - wx) + v111 * wx;
    float b0 = a00 * (1.f - wy) + a10 * wy;
    float b1 = a01 * (1.f - wy) + a11 * wy;
    dst[r] = b0 * (1.f - wz) + b1 * wz;
}

// ----------------- gather loss kernel (scales 1,2) --------------------------
__global__ void elasticity_loss_v4_kernel(const float* __restrict__ def,
                                          const float* __restrict__ img,
                                          int B, int X, int Y, int Z,
                                          float inv_n,
                                          float* __restrict__ out) {
    const int Zg = Z >> 2;
    long long total = (long long)B * X * Y * Zg;
    long long idx = (long long)blockIdx.x * blockDim.x + threadIdx.x;
    float val = 0.f;
    if (idx < total) {
        int zg = (int)(idx % Zg);
        long long t = idx / Zg;
        int y = (int)(t % Y);
        t /= Y;
        int x = (int)(t % X);
        int b = (int)(t / X);
        int z0 = zg << 2;

        long long vol = (long long)X * Y * Z;
        const float* base0 = def + ((long long)b * 3 + 0) * vol;
        const float* base1 = def + ((long long)b * 3 + 1) * vol;
        const float* base2 = def + ((long long)b * 3 + 2) * vol;
        const float* base3 = img + (long long)b * vol;
        const float* bases[4] = {base0, base1, base2, base3};

        long long sX = (long long)Y * Z;
        long long c = (long long)x * sX + (long long)y * Z + z0;
        long long cxm = (x > 0) ? c - sX : c;
        long long cxp = (x < X - 1) ? c + sX : c;
        long long cym = (y > 0) ? c - Z : c;
        long long cyp = (y < Y - 1) ? c + Z : c;
        long long czm = (z0 > 0) ? c - 1 : c;
        long long czp = (z0 + 4 < Z) ? c + 4 : c;

        float C[4][4], XM[4][4], XP[4][4], YM[4][4], YP[4][4];
        float ZM[4], ZP[4];
#pragma unroll
        for (int f = 0; f < 4; ++f) {
            const float* p = bases[f];
            float4 tc = *(const float4*)(p + c);
            float4 txm = *(const float4*)(p + cxm);
            float4 txp = *(const float4*)(p + cxp);
            float4 tym = *(const float4*)(p + cym);
            float4 typ = *(const float4*)(p + cyp);
            ZM[f] = p[czm];
            ZP[f] = p[czp];
            C[f][0] = tc.x;  C[f][1] = tc.y;  C[f][2] = tc.z;  C[f][3] = tc.w;
            XM[f][0] = txm.x; XM[f][1] = txm.y; XM[f][2] = txm.z; XM[f][3] = txm.w;
            XP[f][0] = txp.x; XP[f][1] = txp.y; XP[f][2] = txp.z; XP[f][3] = txp.w;
            YM[f][0] = tym.x; YM[f][1] = tym.y; YM[f][2] = tym.z; YM[f][3] = tym.w;
            YP[f][0] = typ.x; YP[f][1] = typ.y; YP[f][2] = typ.z; YP[f][3] = typ.w;
        }

        const bool xlo = (x == 0), xhi = (x == X - 1);
        const bool ylo = (y == 0), yhi = (y == Y - 1);
        const bool zlo = (z0 == 0), zhi = (z0 + 4 == Z);

        float GX[4][4], GY[4][4], GZ[4][4];
#pragma unroll
        for (int f = 0; f < 4; ++f) {
#pragma unroll
            for (int i = 0; i < 4; ++i) {
                GX[f][i] = xlo ? (XP[f][i] - C[f][i])
                               : (xhi ? (C[f][i] - XM[f][i])
                                      : 0.5f * (XP[f][i] - XM[f][i]));
                GY[f][i] = ylo ? (YP[f][i] - C[f][i])
                               : (yhi ? (C[f][i] - YM[f][i])
                                      : 0.5f * (YP[f][i] - YM[f][i]));
            }
            GZ[f][0] = zlo ? (C[f][1] - C[f][0]) : 0.5f * (C[f][1] - ZM[f]);
            GZ[f][1] = 0.5f * (C[f][2] - C[f][0]);
            GZ[f][2] = 0.5f * (C[f][3] - C[f][1]);
            GZ[f][3] = zhi ? (C[f][3] - C[f][2]) : 0.5f * (ZP[f] - C[f][2]);
        }

        float acc = 0.f;
#pragma unroll
        for (int i = 0; i < 4; ++i) {
            float Exx = GX[0][i], Eyy = GY[1][i], Ezz = GZ[2][i];
            float Exy = 0.5f * (GY[0][i] + GX[1][i]);
            float Exz = 0.5f * (GZ[0][i] + GX[2][i]);
            float Eyz = 0.5f * (GZ[1][i] + GY[2][i]);
            float tr = Exx + Eyy + Ezz;
            float g = sqrtf(GX[3][i] * GX[3][i] + GY[3][i] * GY[3][i] +
                            GZ[3][i] * GZ[3][i]);
            float lam = LAMBDA_0 + KAPPA_LAMBDA * g;
            float mu  = MU_0 + KAPPA_MU * g;
            float energy = 0.5f * lam * tr * tr +
                           mu * (Exx * Exx + Eyy * Eyy + Ezz * Ezz +
                                 2.0f * (Exy * Exy + Exz * Exz + Eyz * Eyz));
            float wgt = BASE_WEIGHT + GRADIENT_SCALING * g;
            acc += wgt * energy;
        }
        val = acc * inv_n;
    }

    for (int off = 32; off > 0; off >>= 1)
        val += __shfl_down(val, off, 64);
    __shared__ float smem[8];
    int lane = threadIdx.x & 63;
    int wid = (int)(threadIdx.x >> 6);
    if (lane == 0) smem[wid] = val;
    __syncthreads();
    if (threadIdx.x == 0) {
        float s = 0.f;
        int nw = (int)(blockDim.x >> 6);
        for (int i = 0; i < nw; ++i) s += smem[i];
        atomicAdd(out, s);
    }
}

static void launch_loss_v4(const float* def, const float* img, int B, int X,
                           int Y, int Z, float* out, hipStream_t stream) {
    const int BLOCK = 256;
    long long nvox = (long long)B * X * Y * Z;
    long long total = nvox >> 2;
    float inv_n = (float)(1.0 / (double)nvox);
    int grid = (int)((total + BLOCK - 1) / BLOCK);
    elasticity_loss_v4_kernel<<<grid, BLOCK, 0, stream>>>(def, img, B, X, Y, Z,
                                                          inv_n, out);
}

extern "C" void kernel_launch(void* const* d_in, const int* in_sizes, int n_in,
                              void* d_out, int out_size, void* d_ws, size_t ws_size,
                              hipStream_t stream) {
    const float* def = (const float*)d_in[0];   // (2,3,160,192,160)
    const float* img = (const float*)d_in[1];   // (2,1,160,192,160)
    float* out = (float*)d_out;

    const int B = 2;
    const int X0 = 160, Y0 = 192, Z0 = 160;

    hipMemsetAsync(out, 0, sizeof(float), stream);

    const int BLOCK = 256;

    // ---------------- scale 0: streaming-x LDS stencil (R3) ----------------
    {
        long long nvox = (long long)B * X0 * Y0 * Z0;
        float inv_n = (float)(1.0 / (double)nvox);
        int nby = Y0 / TY;   // 6
        int nbz = Z0 / TZ;   // 5
        int nbx = X0 / CX;   // 16
        int grid = B * nby * nbz * nbx;   // 960
        elasticity_stream_kernel<<<grid, 256, 0, stream>>>(def, img, X0, Y0, Z0,
                                                           nby, nbz, nbx,
                                                           inv_n, out);
    }

    // workspace layout
    const int X2 = 80, Y2 = 96, Z2 = 80;
    const int X4 = 40, Y4 = 48, Z4 = 40;
    long long vol2 = (long long)X2 * Y2 * Z2;
    long long vol4 = (long long)X4 * Y4 * Z4;

    float* def2 = (float*)d_ws;
    float* img2 = def2 + (long long)B * 3 * vol2;
    float* def4 = img2 + (long long)B * vol2;
    float* img4 = def4 + (long long)B * 3 * vol4;

    // ---------------- scale 1 (x2 downsample, fused all-8-maps) -------------
    {
        float rx = (float)((double)(X0 - 1) / (double)(X2 - 1));
        float ry = (float)((double)(Y0 - 1) / (double)(Y2 - 1));
        float rz = (float)((double)(Z0 - 1) / (double)(Z2 - 1));
        long long total = 8LL * vol2;
        int g = (int)((total + BLOCK - 1) / BLOCK);
        downsample_all8_kernel<<<g, BLOCK, 0, stream>>>(def, img, def2, img2,
                                                        X0, Y0, Z0, X2, Y2, Z2,
                                                        rx, ry, rz);
        launch_loss_v4(def2, img2, B, X2, Y2, Z2, out, stream);
    }

    // ---------------- scale 2 (x4 downsample, from original) ----------------
    {
        float rx = (float)((double)(X0 - 1) / (double)(X4 - 1));
        float ry = (float)((double)(Y0 - 1) / (double)(Y4 - 1));
        float rz = (float)((double)(Z0 - 1) / (double)(Z4 - 1));
        long long total = 8LL * vol4;
        int g = (int)((total + BLOCK - 1) / BLOCK);
        downsample_all8_kernel<<<g, BLOCK, 0, stream>>>(def, img, def4, img4,
                                                        X0, Y0, Z0, X4, Y4, Z4,
                                                        rx, ry, rz);
        launch_loss_v4(def4, img4, B, X4, Y4, Z4, out, stream);
    }
}